// Round 1
// baseline (593.999 us; speedup 1.0000x reference)
//
#include <hip/hip_runtime.h>
#include <stdint.h>

#define NN 8192
#define NF 512
#define NH 256

typedef __bf16 bf16_t;
typedef bf16_t bf16x8 __attribute__((ext_vector_type(8)));
typedef float f32x4 __attribute__((ext_vector_type(4)));

// round-to-nearest-even f32 -> bf16 bit pattern
__device__ __forceinline__ unsigned short f2bf(float f) {
  union { float f; unsigned u; } v; v.f = f;
  unsigned r = v.u + 0x7FFFu + ((v.u >> 16) & 1u);
  return (unsigned short)(r >> 16);
}

// async global->LDS, 16B per lane; LDS dest is wave-uniform base + lane*16
__device__ __forceinline__ void gload16(const void* g, void* l) {
  __builtin_amdgcn_global_load_lds(
      (__attribute__((address_space(1))) void*)g,
      (__attribute__((address_space(3))) void*)l, 16, 0, 0);
}

// ---------------- deg + dinv = rsqrt(max(rowsum,1e-12)) ----------------
__global__ void deg_kernel(const float* __restrict__ adj, float* __restrict__ dinv) {
  const int i = blockIdx.x, t = threadIdx.x;
  const float4* row = reinterpret_cast<const float4*>(adj + (long)i * NN);
  float s = 0.f;
#pragma unroll
  for (int it = 0; it < 8; ++it) {
    float4 a = row[it * 256 + t];
    s += a.x + a.y + a.z + a.w;
  }
  for (int o = 32; o; o >>= 1) s += __shfl_down(s, o, 64);
  __shared__ float sm[4];
  if ((t & 63) == 0) sm[t >> 6] = s;
  __syncthreads();
  if (t == 0) {
    float d = sm[0] + sm[1] + sm[2] + sm[3];
    dinv[i] = rsqrtf(fmaxf(d, 1e-12f));
  }
}

// ---------------- A_bf = bf16(dinv_i * adj_ij * dinv_j) ----------------
__global__ void norm_kernel(const float* __restrict__ adj, const float* __restrict__ dinv,
                            unsigned short* __restrict__ Abf) {
  const long idx4 = (long)blockIdx.x * 256 + threadIdx.x; // float4 index
  const int row = (int)(idx4 >> 11);                      // 2048 float4 per row
  const int c4 = (int)(idx4 & 2047);
  const float di = dinv[row];
  float4 a = reinterpret_cast<const float4*>(adj)[idx4];
  float4 dj = reinterpret_cast<const float4*>(dinv)[c4];
  ushort4 o;
  o.x = f2bf(a.x * di * dj.x);
  o.y = f2bf(a.y * di * dj.y);
  o.z = f2bf(a.z * di * dj.z);
  o.w = f2bf(a.w * di * dj.w);
  reinterpret_cast<ushort4*>(Abf)[idx4] = o;
}

// -------- cast x -> Acomb cols [0,512) and xT (LDS-tiled transpose) --------
__global__ void castx_kernel(const float* __restrict__ x, unsigned short* __restrict__ xT,
                             unsigned short* __restrict__ Acomb) {
  __shared__ float tile[64][65];
  const int c0 = blockIdx.x * 64; // feature base
  const int r0 = blockIdx.y * 64; // node base
  const int t = threadIdx.x;
#pragma unroll
  for (int it = 0; it < 16; ++it) {
    int e = it * 256 + t;
    int r = e >> 6, c = e & 63;
    float v = x[(long)(r0 + r) * NF + c0 + c];
    tile[r][c] = v;
    Acomb[(long)(r0 + r) * 1536 + c0 + c] = f2bf(v);
  }
  __syncthreads();
#pragma unroll
  for (int it = 0; it < 16; ++it) {
    int e = it * 256 + t;
    int rr = e >> 6, cc = e & 63;
    xT[(long)(c0 + rr) * NN + r0 + cc] = f2bf(tile[cc][rr]);
  }
}

// -------- cast cheb_W [1536,256] -> WcT [256][1536] bf16 --------
__global__ void castw_kernel(const float* __restrict__ W, unsigned short* __restrict__ WT) {
  __shared__ float tile[64][65];
  const int c0 = blockIdx.x * 64; // n base (0..255)
  const int r0 = blockIdx.y * 64; // k base (0..1535)
  const int t = threadIdx.x;
#pragma unroll
  for (int it = 0; it < 16; ++it) {
    int e = it * 256 + t;
    int r = e >> 6, c = e & 63;
    tile[r][c] = W[(long)(r0 + r) * NH + c0 + c];
  }
  __syncthreads();
#pragma unroll
  for (int it = 0; it < 16; ++it) {
    int e = it * 256 + t;
    int rr = e >> 6, cc = e & 63;
    WT[(long)(c0 + rr) * 1536 + r0 + cc] = f2bf(tile[cc][rr]);
  }
}

// ---------------- bf16 MFMA GEMM, C = A @ B with B given as BT [N][K] ----------------
// 128x128 tile, BK=64, 4 waves (2x2), each wave 64x64 = 4x4 fragments of 16x16.
// MODE 0: Z1 = -acc  -> Z1T bf16 + Acomb cols [512,1024)
// MODE 1: Z2 = -2*acc - x -> Acomb cols [1024,1536)
// MODE 2: h = relu(acc + cheb_b) -> hout f32
template <int MODE>
__global__ __launch_bounds__(256) void gemm_bt(
    const unsigned short* __restrict__ A, const unsigned short* __restrict__ BT,
    const int lda, const int ldbt, const int kdim,
    const float* __restrict__ xf32, const float* __restrict__ chebb,
    unsigned short* __restrict__ Z1T, unsigned short* __restrict__ Acomb,
    float* __restrict__ hout) {
  __shared__ unsigned short As[128 * 64];
  __shared__ unsigned short Bs[128 * 64];
  const int tid = threadIdx.x;
  const int w = tid >> 6, l = tid & 63;
  const int wr = w >> 1, wc = w & 1;
  const int bx = blockIdx.x, by = blockIdx.y;
  const int aRow0 = by * 128, bRow0 = bx * 128;
  const int lrow8 = l >> 3;     // row within 8-row chunk
  const int lk8 = (l & 7) * 8;  // k elem offset within chunk row
  f32x4 acc[4][4] = {};

  for (int k0 = 0; k0 < kdim; k0 += 64) {
    __syncthreads();
#pragma unroll
    for (int i = 0; i < 4; ++i) {
      const int ch = w * 4 + i; // chunk 0..15, 8 rows x 64 k each (1024B)
      gload16(A + (long)(aRow0 + ch * 8 + lrow8) * lda + k0 + lk8, &As[ch * 512]);
      gload16(BT + (long)(bRow0 + ch * 8 + lrow8) * ldbt + k0 + lk8, &Bs[ch * 512]);
    }
    __syncthreads(); // compiler drains vmcnt(0) before s_barrier -> LDS valid
#pragma unroll
    for (int ks = 0; ks < 2; ++ks) {
      bf16x8 av[4], bv[4];
#pragma unroll
      for (int m = 0; m < 4; ++m)
        av[m] = *reinterpret_cast<const bf16x8*>(
            &As[(wr * 64 + m * 16 + (l & 15)) * 64 + ks * 32 + (l >> 4) * 8]);
#pragma unroll
      for (int n = 0; n < 4; ++n)
        bv[n] = *reinterpret_cast<const bf16x8*>(
            &Bs[(wc * 64 + n * 16 + (l & 15)) * 64 + ks * 32 + (l >> 4) * 8]);
#pragma unroll
      for (int m = 0; m < 4; ++m)
#pragma unroll
        for (int n = 0; n < 4; ++n)
          acc[m][n] = __builtin_amdgcn_mfma_f32_16x16x32_bf16(av[m], bv[n], acc[m][n], 0, 0, 0);
    }
  }

  // epilogue: C elem (row = base + (l>>4)*4 + j, col = base + (l&15))  [m89-verified]
  const int lr = (l >> 4) * 4;
  const int lc = l & 15;
#pragma unroll
  for (int m = 0; m < 4; ++m) {
#pragma unroll
    for (int n = 0; n < 4; ++n) {
      const int rowb = aRow0 + wr * 64 + m * 16 + lr;
      const int col = bRow0 + wc * 64 + n * 16 + lc;
      if (MODE == 0) {
        unsigned short pv[4];
#pragma unroll
        for (int j = 0; j < 4; ++j) pv[j] = f2bf(-acc[m][n][j]);
        *reinterpret_cast<ushort4*>(&Z1T[(long)col * NN + rowb]) =
            *reinterpret_cast<ushort4*>(pv);
#pragma unroll
        for (int j = 0; j < 4; ++j)
          Acomb[(long)(rowb + j) * 1536 + 512 + col] = pv[j];
      } else if (MODE == 1) {
#pragma unroll
        for (int j = 0; j < 4; ++j) {
          float xv = xf32[(long)(rowb + j) * NF + col];
          Acomb[(long)(rowb + j) * 1536 + 1024 + col] = f2bf(-2.f * acc[m][n][j] - xv);
        }
      } else {
        const float bias = chebb[col];
#pragma unroll
        for (int j = 0; j < 4; ++j) {
          float v = acc[m][n][j] + bias;
          hout[(long)(rowb + j) * NH + col] = v > 0.f ? v : 0.f;
        }
      }
    }
  }
}

// ---------------- u[i][c] = sum_k h[i][k] * gc2_W[k][c] ----------------
__global__ void u_kernel(const float* __restrict__ h, const float* __restrict__ gw,
                         float* __restrict__ u) {
  const int i = blockIdx.x, t = threadIdx.x;
  float hv = h[(long)i * NH + t];
  float p0 = hv * gw[t * 2];
  float p1 = hv * gw[t * 2 + 1];
  for (int o = 32; o; o >>= 1) {
    p0 += __shfl_down(p0, o, 64);
    p1 += __shfl_down(p1, o, 64);
  }
  __shared__ float s0[4], s1[4];
  if ((t & 63) == 0) { s0[t >> 6] = p0; s1[t >> 6] = p1; }
  __syncthreads();
  if (t == 0) {
    u[i * 2] = s0[0] + s0[1] + s0[2] + s0[3];
    u[i * 2 + 1] = s1[0] + s1[1] + s1[2] + s1[3];
  }
}

// ---------------- logits[i][c] = adj[i,:] . u[:,c] + gc2_b[c] ----------------
__global__ void logits_kernel(const float* __restrict__ adj, const float* __restrict__ u,
                              const float* __restrict__ gb, float* __restrict__ logits) {
  const int i = blockIdx.x, t = threadIdx.x;
  const float4* row = reinterpret_cast<const float4*>(adj + (long)i * NN);
  const float2* uv = reinterpret_cast<const float2*>(u);
  float a0 = 0.f, a1 = 0.f;
#pragma unroll
  for (int it = 0; it < 8; ++it) {
    const int j4 = it * 256 + t;
    float4 a = row[j4];
    float2 u0 = uv[j4 * 4], u1 = uv[j4 * 4 + 1], u2 = uv[j4 * 4 + 2], u3 = uv[j4 * 4 + 3];
    a0 += a.x * u0.x + a.y * u1.x + a.z * u2.x + a.w * u3.x;
    a1 += a.x * u0.y + a.y * u1.y + a.z * u2.y + a.w * u3.y;
  }
  for (int o = 32; o; o >>= 1) {
    a0 += __shfl_down(a0, o, 64);
    a1 += __shfl_down(a1, o, 64);
  }
  __shared__ float s0[4], s1[4];
  if ((t & 63) == 0) { s0[t >> 6] = a0; s1[t >> 6] = a1; }
  __syncthreads();
  if (t == 0) {
    logits[i * 2] = s0[0] + s0[1] + s0[2] + s0[3] + gb[0];
    logits[i * 2 + 1] = s1[0] + s1[1] + s1[2] + s1[3] + gb[1];
  }
}

// ---------------- out[c] = max_i logits[i][c] ----------------
__global__ void maxpool_kernel(const float* __restrict__ logits, float* __restrict__ out) {
  const int t = threadIdx.x;
  float m0 = -3.4e38f, m1 = -3.4e38f;
  for (int i = t; i < NN; i += 256) {
    m0 = fmaxf(m0, logits[i * 2]);
    m1 = fmaxf(m1, logits[i * 2 + 1]);
  }
  for (int o = 32; o; o >>= 1) {
    m0 = fmaxf(m0, __shfl_down(m0, o, 64));
    m1 = fmaxf(m1, __shfl_down(m1, o, 64));
  }
  __shared__ float s0[4], s1[4];
  if ((t & 63) == 0) { s0[t >> 6] = m0; s1[t >> 6] = m1; }
  __syncthreads();
  if (t == 0) {
    out[0] = fmaxf(fmaxf(s0[0], s0[1]), fmaxf(s0[2], s0[3]));
    out[1] = fmaxf(fmaxf(s1[0], s1[1]), fmaxf(s1[2], s1[3]));
  }
}

extern "C" void kernel_launch(void* const* d_in, const int* in_sizes, int n_in,
                              void* d_out, int out_size, void* d_ws, size_t ws_size,
                              hipStream_t stream) {
  (void)in_sizes; (void)n_in; (void)out_size; (void)ws_size;
  const float* x = (const float*)d_in[0];       // [8192,512]
  const float* adj = (const float*)d_in[1];     // [8192,8192]
  const float* cheb_W = (const float*)d_in[2];  // [3,512,256] = [1536,256]
  const float* cheb_b = (const float*)d_in[3];  // [256]
  const float* gc2_W = (const float*)d_in[4];   // [256,2]
  const float* gc2_b = (const float*)d_in[5];   // [2]
  float* out = (float*)d_out;                   // [2]

  char* ws = (char*)d_ws;
  unsigned short* Abf   = (unsigned short*)(ws);                 // 128 MiB
  unsigned short* xT    = (unsigned short*)(ws + 134217728L);    // 8 MiB
  unsigned short* Z1T   = (unsigned short*)(ws + 142606336L);    // 8 MiB
  unsigned short* Acomb = (unsigned short*)(ws + 150994944L);    // 24 MiB [x|Z1|Z2]
  unsigned short* WcT   = (unsigned short*)(ws + 176160768L);    // 768 KiB
  float* dinv           = (float*)(ws + 176947200L);             // 32 KiB
  float* h              = (float*)(ws + 176979968L);             // 8 MiB
  float* u              = (float*)(ws + 185368576L);             // 64 KiB
  float* logits         = (float*)(ws + 185434112L);             // 64 KiB

  deg_kernel<<<dim3(NN), dim3(256), 0, stream>>>(adj, dinv);
  norm_kernel<<<dim3(65536), dim3(256), 0, stream>>>(adj, dinv, Abf);
  castx_kernel<<<dim3(8, 128), dim3(256), 0, stream>>>(x, xT, Acomb);
  castw_kernel<<<dim3(4, 24), dim3(256), 0, stream>>>(cheb_W, WcT);
  // Z1 = -(A_norm @ x)
  gemm_bt<0><<<dim3(4, 64), dim3(256), 0, stream>>>(Abf, xT, NN, NN, NN,
      (const float*)nullptr, (const float*)nullptr, Z1T, Acomb, (float*)nullptr);
  // Z2 = -2*(A_norm @ Z1) - x
  gemm_bt<1><<<dim3(4, 64), dim3(256), 0, stream>>>(Abf, Z1T, NN, NN, NN,
      x, (const float*)nullptr, (unsigned short*)nullptr, Acomb, (float*)nullptr);
  // h = relu([x|Z1|Z2] @ [W0;W1;W2] + b)
  gemm_bt<2><<<dim3(2, 64), dim3(256), 0, stream>>>(Acomb, WcT, 1536, 1536, 1536,
      (const float*)nullptr, cheb_b, (unsigned short*)nullptr, (unsigned short*)nullptr, h);
  u_kernel<<<dim3(NN), dim3(256), 0, stream>>>(h, gc2_W, u);
  logits_kernel<<<dim3(NN), dim3(256), 0, stream>>>(adj, u, gc2_b, logits);
  maxpool_kernel<<<dim3(1), dim3(256), 0, stream>>>(logits, out);
}

// Round 2
// 510.556 us; speedup vs baseline: 1.1634x; 1.1634x over previous
//
#include <hip/hip_runtime.h>
#include <stdint.h>

#define NN 8192
#define NF 512
#define NH 256

typedef __bf16 bf16_t;
typedef bf16_t bf16x8 __attribute__((ext_vector_type(8)));
typedef float f32x4 __attribute__((ext_vector_type(4)));

// round-to-nearest-even f32 -> bf16 bit pattern
__device__ __forceinline__ unsigned short f2bf(float f) {
  union { float f; unsigned u; } v; v.f = f;
  unsigned r = v.u + 0x7FFFu + ((v.u >> 16) & 1u);
  return (unsigned short)(r >> 16);
}

// async global->LDS, 16B per lane; LDS dest is wave-uniform base + lane*16
__device__ __forceinline__ void gload16(const void* g, void* l) {
  __builtin_amdgcn_global_load_lds(
      (__attribute__((address_space(1))) void*)g,
      (__attribute__((address_space(3))) void*)l, 16, 0, 0);
}

// ---------------- deg: dinv = rsqrt(max(rowsum,1e-12)), sqd = sqrt(...) ----------------
__global__ void deg_kernel(const float* __restrict__ adj, float* __restrict__ dinv,
                           float* __restrict__ sqd) {
  const int i = blockIdx.x, t = threadIdx.x;
  const float4* row = reinterpret_cast<const float4*>(adj + (long)i * NN);
  float s = 0.f;
#pragma unroll
  for (int it = 0; it < 8; ++it) {
    float4 a = row[it * 256 + t];
    s += a.x + a.y + a.z + a.w;
  }
  for (int o = 32; o; o >>= 1) s += __shfl_down(s, o, 64);
  __shared__ float sm[4];
  if ((t & 63) == 0) sm[t >> 6] = s;
  __syncthreads();
  if (t == 0) {
    float d = fmaxf(sm[0] + sm[1] + sm[2] + sm[3], 1e-12f);
    dinv[i] = rsqrtf(d);
    sqd[i] = sqrtf(d);
  }
}

// ---------------- A_bf = bf16(dinv_i * adj_ij * dinv_j) ----------------
__global__ void norm_kernel(const float* __restrict__ adj, const float* __restrict__ dinv,
                            unsigned short* __restrict__ Abf) {
  const long idx4 = (long)blockIdx.x * 256 + threadIdx.x; // float4 index
  const int row = (int)(idx4 >> 11);                      // 2048 float4 per row
  const int c4 = (int)(idx4 & 2047);
  const float di = dinv[row];
  float4 a = reinterpret_cast<const float4*>(adj)[idx4];
  float4 dj = reinterpret_cast<const float4*>(dinv)[c4];
  ushort4 o;
  o.x = f2bf(a.x * di * dj.x);
  o.y = f2bf(a.y * di * dj.y);
  o.z = f2bf(a.z * di * dj.z);
  o.w = f2bf(a.w * di * dj.w);
  reinterpret_cast<ushort4*>(Abf)[idx4] = o;
}

// -------- cast x -> Acomb cols [0,512) and xT (LDS-tiled transpose) --------
__global__ void castx_kernel(const float* __restrict__ x, unsigned short* __restrict__ xT,
                             unsigned short* __restrict__ Acomb) {
  __shared__ float tile[64][65];
  const int c0 = blockIdx.x * 64; // feature base
  const int r0 = blockIdx.y * 64; // node base
  const int t = threadIdx.x;
#pragma unroll
  for (int it = 0; it < 16; ++it) {
    int e = it * 256 + t;
    int r = e >> 6, c = e & 63;
    float v = x[(long)(r0 + r) * NF + c0 + c];
    tile[r][c] = v;
    Acomb[(long)(r0 + r) * 1536 + c0 + c] = f2bf(v);
  }
  __syncthreads();
#pragma unroll
  for (int it = 0; it < 16; ++it) {
    int e = it * 256 + t;
    int rr = e >> 6, cc = e & 63;
    xT[(long)(c0 + rr) * NN + r0 + cc] = f2bf(tile[cc][rr]);
  }
}

// -------- cast cheb_W [1536,256] -> WcT [256][1536] bf16 --------
__global__ void castw_kernel(const float* __restrict__ W, unsigned short* __restrict__ WT) {
  __shared__ float tile[64][65];
  const int c0 = blockIdx.x * 64; // n base (0..255)
  const int r0 = blockIdx.y * 64; // k base (0..1535)
  const int t = threadIdx.x;
#pragma unroll
  for (int it = 0; it < 16; ++it) {
    int e = it * 256 + t;
    int r = e >> 6, c = e & 63;
    tile[r][c] = W[(long)(r0 + r) * NH + c0 + c];
  }
  __syncthreads();
#pragma unroll
  for (int it = 0; it < 16; ++it) {
    int e = it * 256 + t;
    int rr = e >> 6, cc = e & 63;
    WT[(long)(c0 + rr) * 1536 + r0 + cc] = f2bf(tile[cc][rr]);
  }
}

// ---------------- bf16 MFMA partial GEMM, P[kz] = A[:,krange] @ B[krange,:] ----------------
// 128x128 tile, BK=64, 4 waves (2x2), each wave 64x64 = 4x4 frags of 16x16.
// B given as BT [N][K]. blockIdx.z = K-split index; kLen = K / ksplit.
__global__ __launch_bounds__(256) void gemm_bt(
    const unsigned short* __restrict__ A, const unsigned short* __restrict__ BT,
    const int lda, const int ldbt, const int kLen, const int Nout,
    float* __restrict__ P) {
  __shared__ unsigned short As[128 * 64];
  __shared__ unsigned short Bs[128 * 64];
  const int tid = threadIdx.x;
  const int w = tid >> 6, l = tid & 63;
  const int wr = w >> 1, wc = w & 1;
  const int aRow0 = blockIdx.y * 128, bRow0 = blockIdx.x * 128;
  const int kz = blockIdx.z;
  const int lrow8 = l >> 3;     // row within 8-row chunk
  const int lk8 = (l & 7) * 8;  // k elem offset within chunk row
  f32x4 acc[4][4] = {};
  const int kbeg = kz * kLen, kend = kbeg + kLen;

  for (int k0 = kbeg; k0 < kend; k0 += 64) {
    __syncthreads();
#pragma unroll
    for (int i = 0; i < 4; ++i) {
      const int ch = w * 4 + i; // chunk 0..15, 8 rows x 64 k each (1024B)
      gload16(A + (long)(aRow0 + ch * 8 + lrow8) * lda + k0 + lk8, &As[ch * 512]);
      gload16(BT + (long)(bRow0 + ch * 8 + lrow8) * ldbt + k0 + lk8, &Bs[ch * 512]);
    }
    __syncthreads(); // compiler drains vmcnt(0) before s_barrier -> LDS valid
#pragma unroll
    for (int ks = 0; ks < 2; ++ks) {
      bf16x8 av[4], bv[4];
#pragma unroll
      for (int m = 0; m < 4; ++m)
        av[m] = *reinterpret_cast<const bf16x8*>(
            &As[(wr * 64 + m * 16 + (l & 15)) * 64 + ks * 32 + (l >> 4) * 8]);
#pragma unroll
      for (int n = 0; n < 4; ++n)
        bv[n] = *reinterpret_cast<const bf16x8*>(
            &Bs[(wc * 64 + n * 16 + (l & 15)) * 64 + ks * 32 + (l >> 4) * 8]);
#pragma unroll
      for (int m = 0; m < 4; ++m)
#pragma unroll
        for (int n = 0; n < 4; ++n)
          acc[m][n] = __builtin_amdgcn_mfma_f32_16x16x32_bf16(av[m], bv[n], acc[m][n], 0, 0, 0);
    }
  }

  // C elem (row = base + (l>>4)*4 + j, col = base + (l&15))  [m89-verified]
  float* Pk = P + (long)kz * NN * Nout;
  const int lr = (l >> 4) * 4;
  const int lc = l & 15;
#pragma unroll
  for (int m = 0; m < 4; ++m)
#pragma unroll
    for (int n = 0; n < 4; ++n) {
      const int rowb = aRow0 + wr * 64 + m * 16 + lr;
      const int col = bRow0 + wc * 64 + n * 16 + lc;
#pragma unroll
      for (int j = 0; j < 4; ++j)
        Pk[(long)(rowb + j) * Nout + col] = acc[m][n][j];
    }
}

// ---- reduce1: Z1 = -(sum of partials); write Z1T (bf16, transposed) + Acomb[512:1024) ----
__global__ void reduce1_kernel(const float* __restrict__ P, const int nsplit,
                               unsigned short* __restrict__ Z1T,
                               unsigned short* __restrict__ Acomb) {
  __shared__ float tile[64][65];
  const int c0 = blockIdx.x * 64; // col base (0..511)
  const int r0 = blockIdx.y * 64; // row base (0..8191)
  const int t = threadIdx.x;
#pragma unroll
  for (int it = 0; it < 16; ++it) {
    int e = it * 256 + t;
    int r = e >> 6, c = e & 63;
    long off = (long)(r0 + r) * NF + c0 + c;
    float s = 0.f;
    for (int sp = 0; sp < nsplit; ++sp) s += P[(long)sp * NN * NF + off];
    float z = -s;
    tile[r][c] = z;
    Acomb[(long)(r0 + r) * 1536 + 512 + c0 + c] = f2bf(z);
  }
  __syncthreads();
#pragma unroll
  for (int it = 0; it < 16; ++it) {
    int e = it * 256 + t;
    int rr = e >> 6, cc = e & 63;
    Z1T[(long)(c0 + rr) * NN + r0 + cc] = f2bf(tile[cc][rr]);
  }
}

// ---- reduce2: Z2 = -2*(sum of partials) - x; write Acomb[1024:1536) ----
__global__ void reduce2_kernel(const float* __restrict__ P, const int nsplit,
                               const float* __restrict__ x,
                               unsigned short* __restrict__ Acomb) {
  const long idx4 = (long)blockIdx.x * 256 + threadIdx.x; // float4 idx over 8192*512/4
  const int r = (int)(idx4 >> 7);   // 128 float4 per row
  const int c = (int)(idx4 & 127) * 4;
  float4 s = make_float4(0.f, 0.f, 0.f, 0.f);
  for (int sp = 0; sp < nsplit; ++sp) {
    float4 p = reinterpret_cast<const float4*>(P)[(long)sp * (NN * NF / 4) + idx4];
    s.x += p.x; s.y += p.y; s.z += p.z; s.w += p.w;
  }
  float4 xv = reinterpret_cast<const float4*>(x)[idx4];
  ushort4 o;
  o.x = f2bf(-2.f * s.x - xv.x);
  o.y = f2bf(-2.f * s.y - xv.y);
  o.z = f2bf(-2.f * s.z - xv.z);
  o.w = f2bf(-2.f * s.w - xv.w);
  *reinterpret_cast<ushort4*>(&Acomb[(long)r * 1536 + 1024 + c]) = o;
}

// ---- u: h = relu(sum h-partials + cheb_b); v[i][c] = sqd[i] * (h . gc2_W[:,c]) ----
__global__ void u_kernel(const float* __restrict__ P, const int nsplit,
                         const float* __restrict__ chebb, const float* __restrict__ gw,
                         const float* __restrict__ sqd, float* __restrict__ v) {
  const int i = blockIdx.x, t = threadIdx.x;
  float s = chebb[t];
  for (int sp = 0; sp < nsplit; ++sp) s += P[(long)sp * NN * NH + (long)i * NH + t];
  float hv = s > 0.f ? s : 0.f;
  float p0 = hv * gw[t * 2];
  float p1 = hv * gw[t * 2 + 1];
  for (int o = 32; o; o >>= 1) {
    p0 += __shfl_down(p0, o, 64);
    p1 += __shfl_down(p1, o, 64);
  }
  __shared__ float s0[4], s1[4];
  if ((t & 63) == 0) { s0[t >> 6] = p0; s1[t >> 6] = p1; }
  __syncthreads();
  if (t == 0) {
    float sc = sqd[i];
    v[i * 2] = sc * (s0[0] + s0[1] + s0[2] + s0[3]);
    v[i * 2 + 1] = sc * (s1[0] + s1[1] + s1[2] + s1[3]);
  }
}

// ---- logits[i][c] = sqd[i] * (Abf[i,:] . v[:,c]) + gc2_b[c]  (bf16 adj reconstruction) ----
__global__ void logits_kernel(const unsigned short* __restrict__ Abf,
                              const float* __restrict__ v, const float* __restrict__ sqd,
                              const float* __restrict__ gb, float* __restrict__ logits) {
  const int i = blockIdx.x, t = threadIdx.x;
  const uint4* row = reinterpret_cast<const uint4*>(Abf + (long)i * NN);
  const float4* vv = reinterpret_cast<const float4*>(v);
  float a0 = 0.f, a1 = 0.f;
#pragma unroll
  for (int it = 0; it < 4; ++it) {
    const int idx = it * 256 + t; // uint4 idx, 8 bf16 each
    uint4 pk = row[idx];
    unsigned uu[4] = {pk.x, pk.y, pk.z, pk.w};
#pragma unroll
    for (int q = 0; q < 4; ++q) {
      union { unsigned u; float f; } flo, fhi;
      flo.u = uu[q] << 16;
      fhi.u = uu[q] & 0xFFFF0000u;
      float4 w = vv[idx * 4 + q]; // {v[j][0], v[j][1], v[j+1][0], v[j+1][1]}
      a0 += flo.f * w.x + fhi.f * w.z;
      a1 += flo.f * w.y + fhi.f * w.w;
    }
  }
  for (int o = 32; o; o >>= 1) {
    a0 += __shfl_down(a0, o, 64);
    a1 += __shfl_down(a1, o, 64);
  }
  __shared__ float s0[4], s1[4];
  if ((t & 63) == 0) { s0[t >> 6] = a0; s1[t >> 6] = a1; }
  __syncthreads();
  if (t == 0) {
    float sc = sqd[i];
    logits[i * 2] = sc * (s0[0] + s0[1] + s0[2] + s0[3]) + gb[0];
    logits[i * 2 + 1] = sc * (s1[0] + s1[1] + s1[2] + s1[3]) + gb[1];
  }
}

// ---------------- out[c] = max_i logits[i][c] ----------------
__global__ void maxpool_kernel(const float* __restrict__ logits, float* __restrict__ out) {
  const int t = threadIdx.x;
  float m0 = -3.4e38f, m1 = -3.4e38f;
  for (int i = t; i < NN; i += 256) {
    m0 = fmaxf(m0, logits[i * 2]);
    m1 = fmaxf(m1, logits[i * 2 + 1]);
  }
  for (int o = 32; o; o >>= 1) {
    m0 = fmaxf(m0, __shfl_down(m0, o, 64));
    m1 = fmaxf(m1, __shfl_down(m1, o, 64));
  }
  __shared__ float s0[4], s1[4];
  if ((t & 63) == 0) { s0[t >> 6] = m0; s1[t >> 6] = m1; }
  __syncthreads();
  if (t == 0) {
    out[0] = fmaxf(fmaxf(s0[0], s0[1]), fmaxf(s0[2], s0[3]));
    out[1] = fmaxf(fmaxf(s1[0], s1[1]), fmaxf(s1[2], s1[3]));
  }
}

extern "C" void kernel_launch(void* const* d_in, const int* in_sizes, int n_in,
                              void* d_out, int out_size, void* d_ws, size_t ws_size,
                              hipStream_t stream) {
  (void)in_sizes; (void)n_in; (void)out_size;
  const float* x = (const float*)d_in[0];       // [8192,512]
  const float* adj = (const float*)d_in[1];     // [8192,8192]
  const float* cheb_W = (const float*)d_in[2];  // [3,512,256] = [1536,256]
  const float* cheb_b = (const float*)d_in[3];  // [256]
  const float* gc2_W = (const float*)d_in[4];   // [256,2]
  const float* gc2_b = (const float*)d_in[5];   // [2]
  float* out = (float*)d_out;                   // [2]

  char* ws = (char*)d_ws;
  unsigned short* Abf   = (unsigned short*)(ws);               // 128 MiB, live to end
  unsigned short* BTbuf = (unsigned short*)(ws + 134217728L);  // 8 MiB: xT then Z1T
  unsigned short* Acomb = (unsigned short*)(ws + 142606336L);  // 24 MiB [x|Z1|Z2] bf16
  unsigned short* WcT   = (unsigned short*)(ws + 167772160L);  // 768 KiB (dead after hGEMM)
  float* v              = (float*)(ws + 167772160L);           // 64 KiB, overlays WcT (after hGEMM)
  float* logits         = (float*)(ws + 167837696L);           // 64 KiB, overlays WcT
  float* P              = (float*)(ws + 168558592L);           // split-K partials

  // pick split-K by available workspace (ws_size is constant -> deterministic)
  const long PBASE = 168558592L;
  int ks = 1;
  if (ws_size >= (size_t)(PBASE + 4L * 16777216L + 65536L)) ks = 4;
  else if (ws_size >= (size_t)(PBASE + 2L * 16777216L + 65536L)) ks = 2;
  const long pbytes = (long)ks * 16777216L; // ks * 8192*512*4
  float* dinv = (float*)(ws + PBASE + pbytes);
  float* sqd  = (float*)(ws + PBASE + pbytes + 32768L);

  deg_kernel<<<dim3(NN), dim3(256), 0, stream>>>(adj, dinv, sqd);
  norm_kernel<<<dim3(65536), dim3(256), 0, stream>>>(adj, dinv, Abf);
  castx_kernel<<<dim3(8, 128), dim3(256), 0, stream>>>(x, BTbuf, Acomb);
  castw_kernel<<<dim3(4, 24), dim3(256), 0, stream>>>(cheb_W, WcT);
  // P = split-K partials of A_norm @ x
  gemm_bt<<<dim3(4, 64, ks), dim3(256), 0, stream>>>(Abf, BTbuf, NN, NN, NN / ks, NF, P);
  // Z1 = -(sum P) -> Z1T (into BTbuf) + Acomb[512:1024)
  reduce1_kernel<<<dim3(8, 128), dim3(256), 0, stream>>>(P, ks, BTbuf, Acomb);
  // P = split-K partials of A_norm @ Z1
  gemm_bt<<<dim3(4, 64, ks), dim3(256), 0, stream>>>(Abf, BTbuf, NN, NN, NN / ks, NF, P);
  // Z2 = -2*(sum P) - x -> Acomb[1024:1536)
  reduce2_kernel<<<dim3(4096), dim3(256), 0, stream>>>(P, ks, x, Acomb);
  // P = split-K(2) partials of [x|Z1|Z2] @ [W0;W1;W2]
  gemm_bt<<<dim3(2, 64, 2), dim3(256), 0, stream>>>(Acomb, WcT, 1536, 1536, 768, NH, P);
  // h = relu(sum P + cheb_b); v = diag(sqd) . (h @ gc2_W)
  u_kernel<<<dim3(NN), dim3(256), 0, stream>>>(P, 2, cheb_b, gc2_W, sqd, v);
  // logits via bf16 A_norm reconstruction
  logits_kernel<<<dim3(NN), dim3(256), 0, stream>>>(Abf, v, sqd, gc2_b, logits);
  maxpool_kernel<<<dim3(1), dim3(256), 0, stream>>>(logits, out);
}

// Round 3
// 400.072 us; speedup vs baseline: 1.4847x; 1.2762x over previous
//
#include <hip/hip_runtime.h>
#include <stdint.h>

#define NN 8192
#define NF 512
#define NH 256

typedef __bf16 bf16_t;
typedef bf16_t bf16x8 __attribute__((ext_vector_type(8)));
typedef float f32x4 __attribute__((ext_vector_type(4)));

// round-to-nearest-even f32 -> bf16 bit pattern
__device__ __forceinline__ unsigned short f2bf(float f) {
  union { float f; unsigned u; } v; v.f = f;
  unsigned r = v.u + 0x7FFFu + ((v.u >> 16) & 1u);
  return (unsigned short)(r >> 16);
}

// async global->LDS, 16B per lane; LDS dest is wave-uniform base + lane*16
__device__ __forceinline__ void gload16(const void* g, void* l) {
  __builtin_amdgcn_global_load_lds(
      (__attribute__((address_space(1))) void*)g,
      (__attribute__((address_space(3))) void*)l, 16, 0, 0);
}

// ---- fused: Abf = bf16(adj) raw cast AND dinv = rsqrt(max(rowsum,1e-12)) ----
__global__ void castadj_deg_kernel(const float* __restrict__ adj,
                                   unsigned short* __restrict__ Abf,
                                   float* __restrict__ dinv) {
  const int i = blockIdx.x, t = threadIdx.x;
  const float4* row = reinterpret_cast<const float4*>(adj + (long)i * NN);
  ushort4* orow = reinterpret_cast<ushort4*>(Abf + (long)i * NN);
  float s = 0.f;
#pragma unroll
  for (int it = 0; it < 8; ++it) {
    float4 a = row[it * 256 + t];
    s += a.x + a.y + a.z + a.w;
    ushort4 o;
    o.x = f2bf(a.x); o.y = f2bf(a.y); o.z = f2bf(a.z); o.w = f2bf(a.w);
    orow[it * 256 + t] = o;
  }
  for (int o = 32; o; o >>= 1) s += __shfl_down(s, o, 64);
  __shared__ float sm[4];
  if ((t & 63) == 0) sm[t >> 6] = s;
  __syncthreads();
  if (t == 0) {
    float d = fmaxf(sm[0] + sm[1] + sm[2] + sm[3], 1e-12f);
    dinv[i] = rsqrtf(d);
  }
}

// -------- cast x -> Acomb cols [0,512) raw; yT = (dinv .* x)^T bf16 --------
__global__ void castx_kernel(const float* __restrict__ x, const float* __restrict__ dinv,
                             unsigned short* __restrict__ yT,
                             unsigned short* __restrict__ Acomb) {
  __shared__ float tile[64][65];
  const int c0 = blockIdx.x * 64; // feature base
  const int r0 = blockIdx.y * 64; // node base
  const int t = threadIdx.x;
#pragma unroll
  for (int it = 0; it < 16; ++it) {
    int e = it * 256 + t;
    int r = e >> 6, c = e & 63;
    float v = x[(long)(r0 + r) * NF + c0 + c];
    tile[r][c] = v;
    Acomb[(long)(r0 + r) * 1536 + c0 + c] = f2bf(v);
  }
  __syncthreads();
#pragma unroll
  for (int it = 0; it < 16; ++it) {
    int e = it * 256 + t;
    int rr = e >> 6, cc = e & 63;
    const int node = r0 + cc;
    yT[(long)(c0 + rr) * NN + node] = f2bf(tile[cc][rr] * dinv[node]);
  }
}

// -------- cast cheb_W [1536,256] -> WcT [256][1536] bf16 --------
__global__ void castw_kernel(const float* __restrict__ W, unsigned short* __restrict__ WT) {
  __shared__ float tile[64][65];
  const int c0 = blockIdx.x * 64; // n base (0..255)
  const int r0 = blockIdx.y * 64; // k base (0..1535)
  const int t = threadIdx.x;
#pragma unroll
  for (int it = 0; it < 16; ++it) {
    int e = it * 256 + t;
    int r = e >> 6, c = e & 63;
    tile[r][c] = W[(long)(r0 + r) * NH + c0 + c];
  }
  __syncthreads();
#pragma unroll
  for (int it = 0; it < 16; ++it) {
    int e = it * 256 + t;
    int rr = e >> 6, cc = e & 63;
    WT[(long)(c0 + rr) * 1536 + r0 + cc] = f2bf(tile[cc][rr]);
  }
}

// ---------------- bf16 MFMA partial GEMM, P[kz] = A[:,krange] @ B[krange,:] ----------------
// 128x128 tile, BK=64, 4 waves (2x2), each wave 64x64 = 4x4 frags of 16x16.
// B given as BT [N][K]. blockIdx.z = K-split index; kLen = K / ksplit.
// XCD-aware bijective chunked swizzle on (bx,by): blocks sharing an A-panel
// (same by, all bx) get consecutive remapped ids on one XCD -> L2 reuse.
__global__ __launch_bounds__(256) void gemm_bt(
    const unsigned short* __restrict__ A, const unsigned short* __restrict__ BT,
    const int lda, const int ldbt, const int kLen, const int Nout,
    float* __restrict__ P) {
  __shared__ unsigned short As[128 * 64];
  __shared__ unsigned short Bs[128 * 64];
  const int tid = threadIdx.x;
  const int w = tid >> 6, l = tid & 63;
  const int wr = w >> 1, wc = w & 1;
  // swizzle (nwg2d is a multiple of 8 for all our grids)
  const int nwg2d = gridDim.x * gridDim.y;
  const int lin = blockIdx.x + gridDim.x * blockIdx.y;
  const int wg = (lin & 7) * (nwg2d >> 3) + (lin >> 3);
  const int bx = wg % gridDim.x, by = wg / gridDim.x;
  const int aRow0 = by * 128, bRow0 = bx * 128;
  const int kz = blockIdx.z;
  const int lrow8 = l >> 3;     // row within 8-row chunk
  const int lk8 = (l & 7) * 8;  // k elem offset within chunk row
  f32x4 acc[4][4] = {};
  const int kbeg = kz * kLen, kend = kbeg + kLen;

  for (int k0 = kbeg; k0 < kend; k0 += 64) {
    __syncthreads();
#pragma unroll
    for (int i = 0; i < 4; ++i) {
      const int ch = w * 4 + i; // chunk 0..15, 8 rows x 64 k each (1024B)
      gload16(A + (long)(aRow0 + ch * 8 + lrow8) * lda + k0 + lk8, &As[ch * 512]);
      gload16(BT + (long)(bRow0 + ch * 8 + lrow8) * ldbt + k0 + lk8, &Bs[ch * 512]);
    }
    __syncthreads(); // compiler drains vmcnt(0) before s_barrier -> LDS valid
#pragma unroll
    for (int ks = 0; ks < 2; ++ks) {
      bf16x8 av[4], bv[4];
#pragma unroll
      for (int m = 0; m < 4; ++m)
        av[m] = *reinterpret_cast<const bf16x8*>(
            &As[(wr * 64 + m * 16 + (l & 15)) * 64 + ks * 32 + (l >> 4) * 8]);
#pragma unroll
      for (int n = 0; n < 4; ++n)
        bv[n] = *reinterpret_cast<const bf16x8*>(
            &Bs[(wc * 64 + n * 16 + (l & 15)) * 64 + ks * 32 + (l >> 4) * 8]);
#pragma unroll
      for (int m = 0; m < 4; ++m)
#pragma unroll
        for (int n = 0; n < 4; ++n)
          acc[m][n] = __builtin_amdgcn_mfma_f32_16x16x32_bf16(av[m], bv[n], acc[m][n], 0, 0, 0);
    }
  }

  // C elem (row = base + (l>>4)*4 + j, col = base + (l&15))  [m89-verified]
  float* Pk = P + (long)kz * NN * Nout;
  const int lr = (l >> 4) * 4;
  const int lc = l & 15;
#pragma unroll
  for (int m = 0; m < 4; ++m)
#pragma unroll
    for (int n = 0; n < 4; ++n) {
      const int rowb = aRow0 + wr * 64 + m * 16 + lr;
      const int col = bRow0 + wc * 64 + n * 16 + lc;
#pragma unroll
      for (int j = 0; j < 4; ++j)
        Pk[(long)(rowb + j) * Nout + col] = acc[m][n][j];
    }
}

// ---- reduce1: S = sum partials (= Abf @ y); Z1 = -dinv.*S ----
// writes Acomb[512:1024) = bf16(Z1) and Z1T = bf16(dinv.*Z1)^T (next GEMM's B)
__global__ void reduce1_kernel(const float* __restrict__ P, const int nsplit,
                               const float* __restrict__ dinv,
                               unsigned short* __restrict__ Z1T,
                               unsigned short* __restrict__ Acomb) {
  __shared__ float tile[64][65];
  const int c0 = blockIdx.x * 64; // col base (0..511)
  const int r0 = blockIdx.y * 64; // row base (0..8191)
  const int t = threadIdx.x;
#pragma unroll
  for (int it = 0; it < 16; ++it) {
    int e = it * 256 + t;
    int r = e >> 6, c = e & 63;
    long off = (long)(r0 + r) * NF + c0 + c;
    float s = 0.f;
    for (int sp = 0; sp < nsplit; ++sp) s += P[(long)sp * NN * NF + off];
    const float di = dinv[r0 + r];
    float z = -di * s;
    tile[r][c] = di * z; // scaled operand for next GEMM
    Acomb[(long)(r0 + r) * 1536 + 512 + c0 + c] = f2bf(z);
  }
  __syncthreads();
#pragma unroll
  for (int it = 0; it < 16; ++it) {
    int e = it * 256 + t;
    int rr = e >> 6, cc = e & 63;
    Z1T[(long)(c0 + rr) * NN + r0 + cc] = f2bf(tile[cc][rr]);
  }
}

// ---- reduce2: Z2 = -2*dinv.*(sum partials) - x; write Acomb[1024:1536) ----
__global__ void reduce2_kernel(const float* __restrict__ P, const int nsplit,
                               const float* __restrict__ x, const float* __restrict__ dinv,
                               unsigned short* __restrict__ Acomb) {
  const long idx4 = (long)blockIdx.x * 256 + threadIdx.x; // float4 idx over 8192*512/4
  const int r = (int)(idx4 >> 7);   // 128 float4 per row
  const int c = (int)(idx4 & 127) * 4;
  float4 s = make_float4(0.f, 0.f, 0.f, 0.f);
  for (int sp = 0; sp < nsplit; ++sp) {
    float4 p = reinterpret_cast<const float4*>(P)[(long)sp * (NN * NF / 4) + idx4];
    s.x += p.x; s.y += p.y; s.z += p.z; s.w += p.w;
  }
  const float m2d = -2.f * dinv[r];
  float4 xv = reinterpret_cast<const float4*>(x)[idx4];
  ushort4 o;
  o.x = f2bf(m2d * s.x - xv.x);
  o.y = f2bf(m2d * s.y - xv.y);
  o.z = f2bf(m2d * s.z - xv.z);
  o.w = f2bf(m2d * s.w - xv.w);
  *reinterpret_cast<ushort4*>(&Acomb[(long)r * 1536 + 1024 + c]) = o;
}

// ---- u: h = relu(sum h-partials + cheb_b); v[i][c] = h . gc2_W[:,c] ----
__global__ void u_kernel(const float* __restrict__ P, const int nsplit,
                         const float* __restrict__ chebb, const float* __restrict__ gw,
                         float* __restrict__ v) {
  const int i = blockIdx.x, t = threadIdx.x;
  float s = chebb[t];
  for (int sp = 0; sp < nsplit; ++sp) s += P[(long)sp * NN * NH + (long)i * NH + t];
  float hv = s > 0.f ? s : 0.f;
  float p0 = hv * gw[t * 2];
  float p1 = hv * gw[t * 2 + 1];
  for (int o = 32; o; o >>= 1) {
    p0 += __shfl_down(p0, o, 64);
    p1 += __shfl_down(p1, o, 64);
  }
  __shared__ float s0[4], s1[4];
  if ((t & 63) == 0) { s0[t >> 6] = p0; s1[t >> 6] = p1; }
  __syncthreads();
  if (t == 0) {
    v[i * 2] = s0[0] + s0[1] + s0[2] + s0[3];
    v[i * 2 + 1] = s1[0] + s1[1] + s1[2] + s1[3];
  }
}

// ---- logits[i][c] = Abf[i,:] . v[:,c] + gc2_b[c]  (raw bf16 adjacency) ----
__global__ void logits_kernel(const unsigned short* __restrict__ Abf,
                              const float* __restrict__ v,
                              const float* __restrict__ gb, float* __restrict__ logits) {
  const int i = blockIdx.x, t = threadIdx.x;
  const uint4* row = reinterpret_cast<const uint4*>(Abf + (long)i * NN);
  const float4* vv = reinterpret_cast<const float4*>(v);
  float a0 = 0.f, a1 = 0.f;
#pragma unroll
  for (int it = 0; it < 4; ++it) {
    const int idx = it * 256 + t; // uint4 idx, 8 bf16 each
    uint4 pk = row[idx];
    unsigned uu[4] = {pk.x, pk.y, pk.z, pk.w};
#pragma unroll
    for (int q = 0; q < 4; ++q) {
      union { unsigned u; float f; } flo, fhi;
      flo.u = uu[q] << 16;
      fhi.u = uu[q] & 0xFFFF0000u;
      float4 w = vv[idx * 4 + q]; // {v[j][0], v[j][1], v[j+1][0], v[j+1][1]}
      a0 += flo.f * w.x + fhi.f * w.z;
      a1 += flo.f * w.y + fhi.f * w.w;
    }
  }
  for (int o = 32; o; o >>= 1) {
    a0 += __shfl_down(a0, o, 64);
    a1 += __shfl_down(a1, o, 64);
  }
  __shared__ float s0[4], s1[4];
  if ((t & 63) == 0) { s0[t >> 6] = a0; s1[t >> 6] = a1; }
  __syncthreads();
  if (t == 0) {
    logits[i * 2] = s0[0] + s0[1] + s0[2] + s0[3] + gb[0];
    logits[i * 2 + 1] = s1[0] + s1[1] + s1[2] + s1[3] + gb[1];
  }
}

// ---------------- out[c] = max_i logits[i][c] ----------------
__global__ void maxpool_kernel(const float* __restrict__ logits, float* __restrict__ out) {
  const int t = threadIdx.x;
  float m0 = -3.4e38f, m1 = -3.4e38f;
  for (int i = t; i < NN; i += 256) {
    m0 = fmaxf(m0, logits[i * 2]);
    m1 = fmaxf(m1, logits[i * 2 + 1]);
  }
  for (int o = 32; o; o >>= 1) {
    m0 = fmaxf(m0, __shfl_down(m0, o, 64));
    m1 = fmaxf(m1, __shfl_down(m1, o, 64));
  }
  __shared__ float s0[4], s1[4];
  if ((t & 63) == 0) { s0[t >> 6] = m0; s1[t >> 6] = m1; }
  __syncthreads();
  if (t == 0) {
    out[0] = fmaxf(fmaxf(s0[0], s0[1]), fmaxf(s0[2], s0[3]));
    out[1] = fmaxf(fmaxf(s1[0], s1[1]), fmaxf(s1[2], s1[3]));
  }
}

extern "C" void kernel_launch(void* const* d_in, const int* in_sizes, int n_in,
                              void* d_out, int out_size, void* d_ws, size_t ws_size,
                              hipStream_t stream) {
  (void)in_sizes; (void)n_in; (void)out_size;
  const float* x = (const float*)d_in[0];       // [8192,512]
  const float* adj = (const float*)d_in[1];     // [8192,8192]
  const float* cheb_W = (const float*)d_in[2];  // [3,512,256] = [1536,256]
  const float* cheb_b = (const float*)d_in[3];  // [256]
  const float* gc2_W = (const float*)d_in[4];   // [256,2]
  const float* gc2_b = (const float*)d_in[5];   // [2]
  float* out = (float*)d_out;                   // [2]

  char* ws = (char*)d_ws;
  unsigned short* Abf   = (unsigned short*)(ws);               // 128 MiB, live to end
  unsigned short* BTbuf = (unsigned short*)(ws + 134217728L);  // 8 MiB: yT then Z1T
  unsigned short* Acomb = (unsigned short*)(ws + 142606336L);  // 24 MiB [x|Z1|Z2] bf16
  unsigned short* WcT   = (unsigned short*)(ws + 167772160L);  // 768 KiB (dead after hGEMM)
  float* v              = (float*)(ws + 167772160L);           // 64 KiB, overlays WcT (after hGEMM)
  float* logits         = (float*)(ws + 167837696L);           // 64 KiB, overlays WcT
  float* P              = (float*)(ws + 168558592L);           // split-K partials

  // pick split-K by available workspace (ws_size is constant -> deterministic)
  const long PBASE = 168558592L;
  int ks = 1;
  if (ws_size >= (size_t)(PBASE + 4L * 16777216L + 65536L)) ks = 4;
  else if (ws_size >= (size_t)(PBASE + 2L * 16777216L + 65536L)) ks = 2;
  const int hks = (ks == 4) ? 4 : ks; // h-GEMM split (P use: hks*8 MiB <= ks*16 MiB)
  const long pbytes = (long)ks * 16777216L; // ks * 8192*512*4
  float* dinv = (float*)(ws + PBASE + pbytes);

  // fused raw bf16 cast of adj + row-degree -> dinv
  castadj_deg_kernel<<<dim3(NN), dim3(256), 0, stream>>>(adj, Abf, dinv);
  // yT = (dinv .* x)^T bf16; Acomb[0:512) = bf16(x)
  castx_kernel<<<dim3(8, 128), dim3(256), 0, stream>>>(x, dinv, BTbuf, Acomb);
  castw_kernel<<<dim3(4, 24), dim3(256), 0, stream>>>(cheb_W, WcT);
  // P = split-K partials of Abf @ y
  gemm_bt<<<dim3(4, 64, ks), dim3(256), 0, stream>>>(Abf, BTbuf, NN, NN, NN / ks, NF, P);
  // Z1 = -dinv.*(sum P) -> Z1T (scaled, into BTbuf) + Acomb[512:1024)
  reduce1_kernel<<<dim3(8, 128), dim3(256), 0, stream>>>(P, ks, dinv, BTbuf, Acomb);
  // P = split-K partials of Abf @ (dinv.*Z1)
  gemm_bt<<<dim3(4, 64, ks), dim3(256), 0, stream>>>(Abf, BTbuf, NN, NN, NN / ks, NF, P);
  // Z2 = -2*dinv.*(sum P) - x -> Acomb[1024:1536)
  reduce2_kernel<<<dim3(4096), dim3(256), 0, stream>>>(P, ks, x, dinv, Acomb);
  // P = split-K partials of [x|Z1|Z2] @ [W0;W1;W2]
  gemm_bt<<<dim3(2, 64, hks), dim3(256), 0, stream>>>(Acomb, WcT, 1536, 1536, 1536 / hks, NH, P);
  // h = relu(sum P + cheb_b); v = h @ gc2_W
  u_kernel<<<dim3(NN), dim3(256), 0, stream>>>(P, hks, cheb_b, gc2_W, v);
  // logits = bf16(adj) @ v + b
  logits_kernel<<<dim3(NN), dim3(256), 0, stream>>>(Abf, v, gc2_b, logits);
  maxpool_kernel<<<dim3(1), dim3(256), 0, stream>>>(logits, out);
}